// Round 19
// baseline (40.580 us; speedup 1.0000x reference)
//
#include <hip/hip_runtime.h>
#include <hip/hip_bf16.h>

// Problem constants
#define IH 4096
#define IW 4096
#define KH 11
#define KW 11
#define OH (IH - KH + 1)   // 4086
#define OW (IW - KW + 1)   // 4086

// Block tile: 64x64 outputs, 8 waves (512 threads).
// Wave wv -> row band (wv>>1)*16, col half (wv&1)*32 (2 c-tiles of 16).
#define BM 64
#define BN 64
#define TROWS   74          // staged input rows (64 + 10 halo)
#define TSTRIDE 84          // LDS row stride in bf16 (proven ~free conflicts r11-r18)
#define NC4     20          // float4 chunks per staged row (80 floats)
#define NCHUNK  (TROWS * NC4)      // 1480
#define NITER   3                  // ceil(1480/512)
#define TILE_SHORTS (TROWS * TSTRIDE)  // 6216
#define BMAT_SHORTS (KH * 512)         // [11][16][32] bf16 = 5632
// LDS: 2*6216 + 5632 = 18064 shorts = 36128 B -> 4 blocks/CU x 8 waves = 32 waves

#define TILES_X 64
#define NPAIR   2048        // 2 adjacent-x tiles per block

typedef short bf16x4 __attribute__((ext_vector_type(4)));
typedef short bf16x8 __attribute__((ext_vector_type(8)));
typedef float f32x4  __attribute__((ext_vector_type(4)));

__device__ __forceinline__ short f2b(float f) {
    __hip_bfloat16 h = __float2bfloat16(f);   // RNE
    return __builtin_bit_cast(short, h);
}

// ---- setup kernel (r17/r18): banded-Toeplitz B in global scratch ----
// B_kh[k][j] = w[kh][k-j] (banded), stored [kh][j][k]: lane frag = 16B chunk.
__global__ void build_bmat(const float* __restrict__ w, short* __restrict__ bm) {
    const int tid = threadIdx.x;
#pragma unroll
    for (int t = 0; t < 22; ++t) {             // 22*256 = 5632 exact
        const int idx = tid + t * 256;
        const int kh = idx >> 9;
        const int j  = (idx >> 5) & 15;
        const int k  = idx & 31;
        const int d  = k - j;
        const float val = (d >= 0 && d < KW) ? w[kh * KW + d] : 0.f;
        bm[idx] = f2b(val);
    }
}

// ---- staging split (T14): issue global loads early, LDS-write late ----
__device__ __forceinline__ void stage_load(float4 G[NITER],
                                           const float* __restrict__ x,
                                           int gx0, int gy0, int tid) {
#pragma unroll
    for (int it = 0; it < NITER; ++it) {
        const int i = tid + it * 512;
        float4 v = make_float4(0.f, 0.f, 0.f, 0.f);
        if (i < NCHUNK) {
            const int r  = i / NC4;
            const int c4 = i - r * NC4;
            const int gy = gy0 + r;
            const int gx = gx0 + c4 * 4;
            if (gy < IH && gx + 3 < IW) {
                v = *reinterpret_cast<const float4*>(x + (size_t)gy * IW + gx);
            }
        }
        G[it] = v;
    }
}

__device__ __forceinline__ void stage_write(short* __restrict__ tb,
                                            const float4 G[NITER], int tid) {
#pragma unroll
    for (int it = 0; it < NITER; ++it) {
        const int i = tid + it * 512;
        if (i < NCHUNK) {
            const int r  = i / NC4;
            const int c4 = i - r * NC4;
            bf16x4 b = { f2b(G[it].x), f2b(G[it].y), f2b(G[it].z), f2b(G[it].w) };
            *reinterpret_cast<bf16x4*>(&tb[r * TSTRIDE + c4 * 4]) = b;
        }
    }
}

// ---- fragment helpers (r15/r18, verified) — 2 c-tiles per wave ----
__device__ __forceinline__ void loadA2(bf16x8 a[2], const short* __restrict__ ap) {
#pragma unroll
    for (int c = 0; c < 2; ++c) {
        bf16x4 lo = *reinterpret_cast<const bf16x4*>(ap + c * 16);
        bf16x4 hi = *reinterpret_cast<const bf16x4*>(ap + c * 16 + 4);
        a[c] = __builtin_shufflevector(lo, hi, 0, 1, 2, 3, 4, 5, 6, 7);
    }
}

__device__ __forceinline__ void mfma2(f32x4 acc[2], const bf16x8 a[2], bf16x8 b) {
#pragma unroll
    for (int c = 0; c < 2; ++c) {
        acc[c] = __builtin_amdgcn_mfma_f32_16x16x32_bf16(a[c], b, acc[c], 0, 0, 0);
    }
}

// ---- per-tile MFMA compute, pipelined over kh (r15 core, 16x32/wave) ----
// out[oy0+i][ox0+j] = sum_kh A_kh*B_kh; A_kh[i][k] = X[oy0+kh+i][ox0+k],
// B_kh[k][j] = w[kh][k-j]. A row = lane&15, B col = lane&15,
// C/D col=lane&15,row=(lane>>4)*4+reg.
__device__ __forceinline__ void compute_tile(const short* __restrict__ tb,
                                             const short* __restrict__ bmat,
                                             float bv, float* __restrict__ out,
                                             int gx0, int gy0,
                                             int wr, int ch, int g, int li) {
    f32x4 acc[2] = {};
    const short* ap = &tb[(16 * wr + li) * TSTRIDE + ch * 32 + g * 8];
    const short* bp = &bmat[li * 32 + g * 8];

    bf16x8 Ae[2], Ao[2], Be, Bo;
    loadA2(Ae, ap);                                       // kh = 0
    Be = *reinterpret_cast<const bf16x8*>(bp);

#pragma unroll 1
    for (int kh2 = 0; kh2 < 5; ++kh2) {
        loadA2(Ao, ap + TSTRIDE);                         // kh odd
        Bo = *reinterpret_cast<const bf16x8*>(bp + 512);
        mfma2(acc, Ae, Be);                               // compute even
        ap += 2 * TSTRIDE;
        bp += 1024;
        loadA2(Ae, ap);                                   // kh next even
        Be = *reinterpret_cast<const bf16x8*>(bp);
        mfma2(acc, Ao, Bo);                               // compute odd
    }
    mfma2(acc, Ae, Be);                                   // kh = 10

#pragma unroll
    for (int c = 0; c < 2; ++c) {
        const int ox = gx0 + ch * 32 + c * 16 + li;
        if (ox < OW) {
#pragma unroll
            for (int r = 0; r < 4; ++r) {
                const int oy = gy0 + wr * 16 + g * 4 + r;
                if (oy < OH) {
                    out[(size_t)oy * OW + ox] = acc[c][r] + bv;
                }
            }
        }
    }
}

// 512-thread block, 2-tile chain, double-buffered tile, B in LDS (copied
// from global scratch). T14 issue-early/write-late; in-compute loads are
// LDS-only so staged vmem loads never pollute a compute waitcnt (r17 lesson).
// 36.1 KB LDS + ~56 VGPR -> 4 blocks x 8 waves = 32 waves/CU ceiling.
__global__ __launch_bounds__(512)
void conv2d_w8(const float* __restrict__ x,
               const short* __restrict__ bg,
               const float* __restrict__ bias,
               float* __restrict__ out) {
    __shared__ short buf[2][TILE_SHORTS];   // 2 x 12432 B
    __shared__ short bmat[BMAT_SHORTS];     // 11264 B (total 36128 B)

    const int tid = threadIdx.x;
    // XCD-bijective swizzle (2048 % 8 == 0): each XCD gets 256 contiguous
    // pairs = 8 full tile rows -> halo re-reads hit the same L2.
    const int pair = (blockIdx.x & 7) * (NPAIR / 8) + (blockIdx.x >> 3);
    const int t0   = pair * 2;               // even -> t0,t0+1 share a row
    const int gy0  = (t0 >> 6) * BM;
    const int gxb  = (t0 & (TILES_X - 1)) * BN;

    const int lane = tid & 63;
    const int wv   = tid >> 6;      // 0..7
    const int wr   = wv >> 1;       // row band 0..3
    const int ch   = wv & 1;        // col half 0..1
    const int g    = lane >> 4;
    const int li   = lane & 15;
    const float bv = bias[0];

    // ---- Prologue: stage tile 0 + copy B from global scratch ----
    {
        float4 G0[NITER];
        stage_load(G0, x, gxb, gy0, tid);
        stage_write(buf[0], G0, tid);
    }
#pragma unroll
    for (int t = 0; t < 2; ++t) {              // 704 int4 chunks
        const int idx = tid + t * 512;
        if (idx < (BMAT_SHORTS * 2) / 16) {
            reinterpret_cast<int4*>(bmat)[idx] =
                reinterpret_cast<const int4*>(bg)[idx];
        }
    }
    __syncthreads();

    // ---- T14: issue tile 1's loads, compute tile 0, write, compute ----
    float4 G[NITER];
    stage_load(G, x, gxb + BN, gy0, tid);
    __builtin_amdgcn_sched_barrier(0);       // keep loads above compute

    compute_tile(buf[0], bmat, bv, out, gxb, gy0, wr, ch, g, li);

    stage_write(buf[1], G, tid);
    __syncthreads();                         // publish tile 1

    compute_tile(buf[1], bmat, bv, out, gxb + BN, gy0, wr, ch, g, li);
}

extern "C" void kernel_launch(void* const* d_in, const int* in_sizes, int n_in,
                              void* d_out, int out_size, void* d_ws, size_t ws_size,
                              hipStream_t stream) {
    const float* x    = (const float*)d_in[0];
    const float* w    = (const float*)d_in[1];
    const float* bias = (const float*)d_in[2];
    float* out        = (float*)d_out;
    short* bm         = (short*)d_ws;        // 11264 B of scratch

    build_bmat<<<dim3(1), dim3(256), 0, stream>>>(w, bm);

    dim3 grid(NPAIR);     // 2048 blocks x 2 tiles
    dim3 block(512);
    conv2d_w8<<<grid, block, 0, stream>>>(x, bm, bias, out);
}